// Round 15
// baseline (177.991 us; speedup 1.0000x reference)
//
#include <hip/hip_runtime.h>
#include <hip/hip_bf16.h>

typedef __bf16 bf16;
typedef __bf16 bf16x8 __attribute__((ext_vector_type(8)));
typedef __bf16 bf16x4 __attribute__((ext_vector_type(4)));
typedef float f32x4 __attribute__((ext_vector_type(4)));

#define HID 1024
#define SEQL 2048
#define NB 4

#define AS1 __attribute__((address_space(1)))
#define AS3 __attribute__((address_space(3)))

// ---- fused prep: casts (x, Wq, Wk, Wo), Wv cast+transpose, bqk concat, cbias, RS zero ----
__global__ __launch_bounds__(256) void cast_all(const float* __restrict__ x,
    const float* __restrict__ Wq, const float* __restrict__ Wk,
    const float* __restrict__ Wv, const float* __restrict__ Wo,
    const float* __restrict__ bq, const float* __restrict__ bk,
    const float* __restrict__ bv, const float* __restrict__ bo,
    bf16* __restrict__ XB, bf16* __restrict__ WQKB, bf16* __restrict__ WOB,
    bf16* __restrict__ WvT, float* __restrict__ bqkv, float* __restrict__ cbias,
    float* __restrict__ RS) {
  __shared__ bf16 tile[64][72];
  const int b = blockIdx.x;
  const int t = threadIdx.x;
  if (b < 11264) {  // plain casts
    const float* src; bf16* dst; long base;
    if (b < 8192) { src = x; dst = XB; base = (long)b * 256; }
    else {
      const int w = (b - 8192) >> 10, r = (b - 8192) & 1023;
      src = (w == 0) ? Wq : (w == 1) ? Wk : Wo;
      dst = (w == 2) ? WOB : WQKB + (long)w * (HID * HID);
      base = (long)r * 256;
    }
    const long i = base + t;
    float4 v = reinterpret_cast<const float4*>(src)[i];
    bf16x4 o = { (bf16)v.x, (bf16)v.y, (bf16)v.z, (bf16)v.w };
    reinterpret_cast<bf16x4*>(dst)[i] = o;
  } else if (b < 11520) {  // Wv -> WvT (cast + 64x64 transpose); WvT[d][h] = Wv[h][d]
    const int tt = b - 11264;
    const int ti = tt >> 4, tj = tt & 15;  // Wv row-block, col-block
    const int r = t >> 2, c0 = (t & 3) * 16;
    const float* src = Wv + ((long)ti * 64 + r) * HID + tj * 64 + c0;
#pragma unroll
    for (int j = 0; j < 4; ++j) {
      float4 v = *reinterpret_cast<const float4*>(src + j * 4);
      tile[r][c0 + j * 4 + 0] = (bf16)v.x;
      tile[r][c0 + j * 4 + 1] = (bf16)v.y;
      tile[r][c0 + j * 4 + 2] = (bf16)v.z;
      tile[r][c0 + j * 4 + 3] = (bf16)v.w;
    }
    __syncthreads();
    bf16* dst = WvT + ((long)tj * 64 + r) * HID + ti * 64 + c0;
    bf16x8 o0, o1;
#pragma unroll
    for (int j = 0; j < 8; ++j) { o0[j] = tile[c0 + j][r]; o1[j] = tile[c0 + 8 + j][r]; }
    *reinterpret_cast<bf16x8*>(dst) = o0;
    *reinterpret_cast<bf16x8*>(dst + 8) = o1;
  } else if (b < 11528) {  // bqk concat [2048]
    const int i = (b - 11520) * 256 + t;
    bqkv[i] = (i < HID) ? bq[i] : bk[i - HID];
  } else if (b < 11560) {  // cbias = Wo . bv + bo  (32 rows per block)
    const int r = (b - 11528) * 32 + (t >> 3);
    const int l8 = t & 7;
    float s = 0.f;
    const float* wr = Wo + (long)r * HID + l8 * 128;
#pragma unroll
    for (int j = 0; j < 32; ++j) {
      float4 v = *reinterpret_cast<const float4*>(wr + j * 4);
      const float* bp = bv + l8 * 128 + j * 4;
      s += v.x * bp[0] + v.y * bp[1] + v.z * bp[2] + v.w * bp[3];
    }
    s += __shfl_xor(s, 1);
    s += __shfl_xor(s, 2);
    s += __shfl_xor(s, 4);
    if (l8 == 0) cbias[r] = s + bo[r];
  } else {  // RS zero [8192]
    RS[(b - 11560) * 256 + t] = 0.0f;
  }
}

// ======== shared pipeline pieces (256x128 tile, BK=32, 512 thr, 3-buf counted vmcnt) ========
#define PIPE_DECLS                                                                        \
  const int lane = t & 63;                                                                \
  const int wid = t >> 6;                                                                 \
  const int wr = (wid >> 1) * 64;                                                         \
  const int wc = (wid & 1) * 64;                                                          \
  const int frow = lane & 15;                                                             \
  const int l = lane >> 4;                                                                \
  const int sr = t >> 2;                                                                  \
  const int scol = (((t & 3) ^ ((t >> 3) & 3)) << 3);                                     \
  int offA[4], offB[4];                                                                   \
  _Pragma("unroll") for (int m = 0; m < 4; ++m) {                                         \
    const int r = wr + m * 16 + frow;                                                     \
    offA[m] = r * 32 + ((l ^ ((r >> 1) & 3)) << 3);                                       \
  }                                                                                       \
  _Pragma("unroll") for (int n = 0; n < 4; ++n) {                                         \
    const int r = wc + n * 16 + frow;                                                     \
    offB[n] = 8192 + r * 32 + ((l ^ ((r >> 1) & 3)) << 3);                                \
  }                                                                                       \
  f32x4 acc[4][4] = {};

#define STAGE(bufi, tile_)                                                                \
  {                                                                                       \
    const int kk = (tile_) << 5;                                                          \
    bf16* lb = &lds[bufi][0];                                                             \
    __builtin_amdgcn_global_load_lds(                                                     \
        (const AS1 void*)(Ab + (long)sr * lda + kk + scol),                               \
        (AS3 void*)(lb + t * 8), 16, 0, 0);                                               \
    __builtin_amdgcn_global_load_lds(                                                     \
        (const AS1 void*)(Ab + (long)(sr + 128) * lda + kk + scol),                       \
        (AS3 void*)(lb + 4096 + t * 8), 16, 0, 0);                                        \
    __builtin_amdgcn_global_load_lds(                                                     \
        (const AS1 void*)(Bb + (long)sr * ldb + kk + scol),                               \
        (AS3 void*)(lb + 8192 + t * 8), 16, 0, 0);                                        \
  }

#define PIPE_LOOP                                                                         \
  STAGE(0, 0);                                                                            \
  STAGE(1, 1);                                                                            \
  asm volatile("s_waitcnt vmcnt(3)" ::: "memory");                                        \
  __builtin_amdgcn_s_barrier();                                                           \
  __builtin_amdgcn_sched_barrier(0);                                                      \
  int rb = 0;                                                                             \
  for (int tt = 0; tt < nt; ++tt) {                                                       \
    const bf16* lb = &lds[rb][0];                                                         \
    bf16x8 af[4], bfr[4];                                                                 \
    _Pragma("unroll") for (int m = 0; m < 4; ++m)                                         \
        af[m] = *reinterpret_cast<const bf16x8*>(lb + offA[m]);                           \
    _Pragma("unroll") for (int n = 0; n < 4; ++n)                                         \
        bfr[n] = *reinterpret_cast<const bf16x8*>(lb + offB[n]);                          \
    int sb = rb + 2; if (sb >= 3) sb -= 3;                                                \
    if (tt + 2 < nt) STAGE(sb, tt + 2);                                                   \
    __builtin_amdgcn_s_setprio(1);                                                        \
    _Pragma("unroll") for (int m = 0; m < 4; ++m)                                         \
      _Pragma("unroll") for (int n = 0; n < 4; ++n)                                       \
          acc[m][n] = __builtin_amdgcn_mfma_f32_16x16x32_bf16(af[m], bfr[n], acc[m][n], 0, 0, 0); \
    __builtin_amdgcn_s_setprio(0);                                                        \
    __builtin_amdgcn_sched_barrier(0);                                                    \
    if (tt + 2 < nt)      { asm volatile("s_waitcnt vmcnt(3)" ::: "memory"); }            \
    else if (tt + 1 < nt) { asm volatile("s_waitcnt vmcnt(0)" ::: "memory"); }            \
    if (tt + 1 < nt) {                                                                    \
      __builtin_amdgcn_s_barrier();                                                       \
      __builtin_amdgcn_sched_barrier(0);                                                  \
    }                                                                                     \
    rb = (rb + 1 == 3) ? 0 : rb + 1;                                                      \
  }

// ---------------- NT GEMM 256x128 (QK projection, U precompute, final) ----------------
// KLIM: causal K-limit (bi+1)*256. RSDIV: v *= 1/rs[bz*SEQL+row] (before bias).
// QKVSC: 1/32 on q columns (after bias). SWZ: XCD-chunked blockIdx swizzle.
template <typename OutT, bool BIAS, bool KLIM, bool RSDIV, bool QKVSC, bool SWZ>
__global__ __launch_bounds__(512, 4)
void gemm_nt(const bf16* __restrict__ A, const bf16* __restrict__ B,
             const float* __restrict__ bias, OutT* __restrict__ C,
             const float* __restrict__ rs,
             int K, int lda, int ldb, int N, long sA, long sB, long sC) {
  int bj, bi;
  if (SWZ) {
    const int lin = blockIdx.x + gridDim.x * blockIdx.y;
    const int chunk = (gridDim.x * gridDim.y) >> 3;
    const int lg = (lin & 7) * chunk + (lin >> 3);
    bj = lg % gridDim.x; bi = lg / gridDim.x;
  } else { bj = blockIdx.x; bi = blockIdx.y; }
  const int bz = blockIdx.z;
  const int t = threadIdx.x;
  const bf16* Ab = A + (long)bz * sA + (long)bi * 256 * lda;
  const bf16* Bb = B + (long)bz * sB + (long)bj * 128 * ldb;
  const int Kend = KLIM ? ((bi + 1) * 256) : K;
  const int nt = Kend >> 5;

  __shared__ bf16 lds[3][12288];
  PIPE_DECLS
  PIPE_LOOP

  const int crow = l * 4;
  const int ccol = frow;
#pragma unroll
  for (int m = 0; m < 4; ++m) {
#pragma unroll
    for (int rr = 0; rr < 4; ++rr) {
      const int rowl = wr + m * 16 + crow + rr;
      const long row = (long)bi * 256 + rowl;
      const float rsv = RSDIV ? (1.0f / rs[(long)bz * SEQL + row]) : 1.0f;
#pragma unroll
      for (int n = 0; n < 4; ++n) {
        const int coll = wc + n * 16 + ccol;
        const int colg = bj * 128 + coll;
        float v = acc[m][n][rr];
        if (RSDIV) v *= rsv;
        if (BIAS)  v += bias[colg];
        if (QKVSC) v *= (colg < HID ? 0.03125f : 1.0f);
        C[(long)bz * sC + row * N + colg] = (OutT)v;
      }
    }
  }
}

// ---------------- scores + W2, one dispatch, grid (17,8,4), XCD-chunked ----------------
// Live blocks (bj <= 2bi+1): P' = exp(q.k^T) causal (max-free), bf16, + atomic row sums.
// Dead blocks (256 = exactly W2's tiles): W2 = U @ X^T (U = Wo.Wv precomputed) — the
// algebraic replacement for the whole V path: out = (P' W2^T)/rs + (Wo.bv + bo).
__global__ __launch_bounds__(512, 4)
void scores_w2(const bf16* __restrict__ QK, const bf16* __restrict__ U,
               const bf16* __restrict__ X,
               bf16* __restrict__ P, bf16* __restrict__ W2, float* __restrict__ rs) {
  const int lin = blockIdx.x + 17 * blockIdx.y + 136 * blockIdx.z;  // grid (17,8,4)
  const int lg = (lin & 7) * 68 + (lin >> 3);
  const int bz = lg / 136;
  const int rem = lg % 136;
  const int bi = rem / 17, bj = rem % 17;
  const int t = threadIdx.x;
  const bool live = (bj <= 2 * bi + 1);
  const bf16 *Ab, *Bb;
  bf16* Cb;
  int lda, ldb;
  if (live) {
    Ab = QK + ((long)bz * SEQL + (long)bi * 256) * (2 * HID);
    Bb = QK + HID + ((long)bz * SEQL + (long)bj * 128) * (2 * HID);
    Cb = P + ((long)bz * SEQL + (long)bi * 256) * SEQL + bj * 128;
    lda = 2 * HID; ldb = 2 * HID;
  } else {
    // dense rank over dead slots: per-bi dead = 15-2bi, prefix = 15bi - bi(bi-1)
    const int rank = bz * 64 + (15 * bi - bi * (bi - 1)) + (bj - (2 * bi + 2));  // 0..255
    const int wz = rank >> 6, r = rank & 63, mi = r >> 4, nj = r & 15;
    Ab = U + (long)mi * 256 * HID;
    Bb = X + ((long)wz * SEQL + (long)nj * 128) * HID;
    Cb = W2 + ((long)wz * HID + (long)mi * 256) * SEQL + nj * 128;
    lda = HID; ldb = HID;
  }
  const int nt = 32;  // K = 1024

  __shared__ bf16 lds[3][12288];
  PIPE_DECLS
  PIPE_LOOP

  const int crow = l * 4;
  const int ccol = frow;
#pragma unroll
  for (int m = 0; m < 4; ++m) {
#pragma unroll
    for (int rr = 0; rr < 4; ++rr) {
      const int rowl = wr + m * 16 + crow + rr;
      float part = 0.0f;
#pragma unroll
      for (int n = 0; n < 4; ++n) {
        const int coll = wc + n * 16 + ccol;
        float v = acc[m][n][rr];
        if (live) {
          const int row = bi * 256 + rowl;
          const int col = bj * 128 + coll;
          v = (col <= row) ? __expf(v) : 0.0f;  // causal mask + max-free exp
          part += v;
        }
        Cb[(long)rowl * SEQL + coll] = (bf16)v;
      }
      if (live) {
        part += __shfl_xor(part, 1);
        part += __shfl_xor(part, 2);
        part += __shfl_xor(part, 4);
        part += __shfl_xor(part, 8);
        if (frow == 0) atomicAdd(&rs[(long)bz * SEQL + bi * 256 + rowl], part);
      }
    }
  }
}

extern "C" void kernel_launch(void* const* d_in, const int* in_sizes, int n_in,
                              void* d_out, int out_size, void* d_ws, size_t ws_size,
                              hipStream_t stream) {
  const float* x  = (const float*)d_in[0];
  const float* Wq = (const float*)d_in[1];
  const float* bq = (const float*)d_in[2];
  const float* Wk = (const float*)d_in[3];
  const float* bk = (const float*)d_in[4];
  const float* Wv = (const float*)d_in[5];
  const float* bv = (const float*)d_in[6];
  const float* Wo = (const float*)d_in[7];
  const float* bo = (const float*)d_in[8];
  float* out = (float*)d_out;

  // workspace (~136.4 MiB), all regions disjoint (XB live through scores_w2):
  //  [0      ,16.78M)  XB bf16 [8192][1024]
  //  [16.78M ,20.97M)  WQKB (Wq,Wk) bf16
  //  [20.97M ,+8KB)    bqkv ; [+8KB,+12KB) cbias
  //  [22.02M ,24.12M)  UB bf16 [1024][1024]
  //  [25.17M ,27.26M)  WvT bf16
  //  [33.55M ,67.11M)  QK bf16 [8192][2048]
  //  [83.89M ,100.66M) W2 bf16 [4][1024][2048]
  //  [100.66M,102.76M) WOB
  //  [102.76M,136.31M) P' bf16 [8192][2048]
  //  [136.31M,+32KB)   RS
  char* ws = (char*)d_ws;
  bf16*  XB    = (bf16*)(ws);
  bf16*  WQKB  = (bf16*)(ws + 16777216L);
  float* bqkv  = (float*)(ws + 20971520L);
  float* cbias = (float*)(ws + 20979712L);
  bf16*  UB    = (bf16*)(ws + 22020096L);
  bf16*  WvT   = (bf16*)(ws + 25165824L);
  bf16*  QK    = (bf16*)(ws + 33554432L);
  bf16*  W2    = (bf16*)(ws + 83886080L);
  bf16*  WOB   = (bf16*)(ws + 100663296L);
  bf16*  P     = (bf16*)(ws + 102760448L);
  float* RS    = (float*)(ws + 136314880L);

  // 1) fused prep
  cast_all<<<11592, 256, 0, stream>>>(x, Wq, Wk, Wv, Wo, bq, bk, bv, bo,
                                      XB, WQKB, WOB, WvT, bqkv, cbias, RS);

  // 2) U = Wo . Wv  (NT: A=Wo, B=Wv^T), tiny 32-block GEMM
  gemm_nt<bf16, false, false, false, false, false><<<dim3(8, 4, 1), 512, 0, stream>>>(
      WOB, WvT, nullptr, UB, nullptr, HID, HID, HID, HID, 0, 0, 0);

  // 3) QK projection: [8192,1024] x [2048,1024]^T; q-cols scaled 1/32 (XCD-swizzled)
  //    512 blocks = one exact round at 2 blk/CU.
  gemm_nt<bf16, true, false, false, true, true><<<dim3(16, 32, 1), 512, 0, stream>>>(
      XB, WQKB, bqkv, QK, nullptr, HID, HID, HID, 2 * HID, 0, 0, 0);

  // 4) P' = exp(q.k^T) causal + atomic row sums; dead causal slots compute W2 = U X^T
  scores_w2<<<dim3(17, 8, NB), 512, 0, stream>>>(QK, UB, XB, P, W2, RS);

  // 5) out = (P' @ W2^T)/rowsum + (Wo.bv + bo)   (causal K-limit; XCD-swizzled)
  gemm_nt<float, true, true, true, false, true><<<dim3(8, 8, NB), 512, 0, stream>>>(
      P, W2, cbias, out, RS, SEQL, SEQL, SEQL, HID,
      (long)SEQL * SEQL, (long)HID * SEQL, (long)SEQL * HID);
}

// Round 16
// 175.325 us; speedup vs baseline: 1.0152x; 1.0152x over previous
//
#include <hip/hip_runtime.h>
#include <hip/hip_bf16.h>

typedef __bf16 bf16;
typedef __bf16 bf16x8 __attribute__((ext_vector_type(8)));
typedef __bf16 bf16x4 __attribute__((ext_vector_type(4)));
typedef float f32x4 __attribute__((ext_vector_type(4)));

#define HID 1024
#define SEQL 2048
#define NB 4

#define AS1 __attribute__((address_space(1)))
#define AS3 __attribute__((address_space(3)))

// ---- fused prep: casts (x, Wq, Wk, Wo), Wv cast+transpose, bqk concat, cbias, RS zero ----
__global__ __launch_bounds__(256) void cast_all(const float* __restrict__ x,
    const float* __restrict__ Wq, const float* __restrict__ Wk,
    const float* __restrict__ Wv, const float* __restrict__ Wo,
    const float* __restrict__ bq, const float* __restrict__ bk,
    const float* __restrict__ bv, const float* __restrict__ bo,
    bf16* __restrict__ XB, bf16* __restrict__ WQKB, bf16* __restrict__ WOB,
    bf16* __restrict__ WvT, float* __restrict__ bqkv, float* __restrict__ cbias,
    float* __restrict__ RS) {
  __shared__ bf16 tile[64][72];
  const int b = blockIdx.x;
  const int t = threadIdx.x;
  if (b < 11264) {  // plain casts
    const float* src; bf16* dst; long base;
    if (b < 8192) { src = x; dst = XB; base = (long)b * 256; }
    else {
      const int w = (b - 8192) >> 10, r = (b - 8192) & 1023;
      src = (w == 0) ? Wq : (w == 1) ? Wk : Wo;
      dst = (w == 2) ? WOB : WQKB + (long)w * (HID * HID);
      base = (long)r * 256;
    }
    const long i = base + t;
    float4 v = reinterpret_cast<const float4*>(src)[i];
    bf16x4 o = { (bf16)v.x, (bf16)v.y, (bf16)v.z, (bf16)v.w };
    reinterpret_cast<bf16x4*>(dst)[i] = o;
  } else if (b < 11520) {  // Wv -> WvT (cast + 64x64 transpose); WvT[d][h] = Wv[h][d]
    const int tt = b - 11264;
    const int ti = tt >> 4, tj = tt & 15;
    const int r = t >> 2, c0 = (t & 3) * 16;
    const float* src = Wv + ((long)ti * 64 + r) * HID + tj * 64 + c0;
#pragma unroll
    for (int j = 0; j < 4; ++j) {
      float4 v = *reinterpret_cast<const float4*>(src + j * 4);
      tile[r][c0 + j * 4 + 0] = (bf16)v.x;
      tile[r][c0 + j * 4 + 1] = (bf16)v.y;
      tile[r][c0 + j * 4 + 2] = (bf16)v.z;
      tile[r][c0 + j * 4 + 3] = (bf16)v.w;
    }
    __syncthreads();
    bf16* dst = WvT + ((long)tj * 64 + r) * HID + ti * 64 + c0;
    bf16x8 o0, o1;
#pragma unroll
    for (int j = 0; j < 8; ++j) { o0[j] = tile[c0 + j][r]; o1[j] = tile[c0 + 8 + j][r]; }
    *reinterpret_cast<bf16x8*>(dst) = o0;
    *reinterpret_cast<bf16x8*>(dst + 8) = o1;
  } else if (b < 11528) {  // bqk concat [2048]
    const int i = (b - 11520) * 256 + t;
    bqkv[i] = (i < HID) ? bq[i] : bk[i - HID];
  } else if (b < 11560) {  // cbias = Wo . bv + bo  (32 rows per block)
    const int r = (b - 11528) * 32 + (t >> 3);
    const int l8 = t & 7;
    float s = 0.f;
    const float* wr = Wo + (long)r * HID + l8 * 128;
#pragma unroll
    for (int j = 0; j < 32; ++j) {
      float4 v = *reinterpret_cast<const float4*>(wr + j * 4);
      const float* bp = bv + l8 * 128 + j * 4;
      s += v.x * bp[0] + v.y * bp[1] + v.z * bp[2] + v.w * bp[3];
    }
    s += __shfl_xor(s, 1);
    s += __shfl_xor(s, 2);
    s += __shfl_xor(s, 4);
    if (l8 == 0) cbias[r] = s + bo[r];
  } else {  // RS zero [8192]
    RS[(b - 11560) * 256 + t] = 0.0f;
  }
}

// ======== shared pipeline pieces (256x128 tile, BK=32, 512 thr, 3-buf counted vmcnt) ========
#define PIPE_DECLS                                                                        \
  const int lane = t & 63;                                                                \
  const int wid = t >> 6;                                                                 \
  const int wr = (wid >> 1) * 64;                                                         \
  const int wc = (wid & 1) * 64;                                                          \
  const int frow = lane & 15;                                                             \
  const int l = lane >> 4;                                                                \
  const int sr = t >> 2;                                                                  \
  const int scol = (((t & 3) ^ ((t >> 3) & 3)) << 3);                                     \
  int offA[4], offB[4];                                                                   \
  _Pragma("unroll") for (int m = 0; m < 4; ++m) {                                         \
    const int r = wr + m * 16 + frow;                                                     \
    offA[m] = r * 32 + ((l ^ ((r >> 1) & 3)) << 3);                                       \
  }                                                                                       \
  _Pragma("unroll") for (int n = 0; n < 4; ++n) {                                         \
    const int r = wc + n * 16 + frow;                                                     \
    offB[n] = 8192 + r * 32 + ((l ^ ((r >> 1) & 3)) << 3);                                \
  }                                                                                       \
  f32x4 acc[4][4] = {};

#define STAGE(bufi, tile_)                                                                \
  {                                                                                       \
    const int kk = (tile_) << 5;                                                          \
    bf16* lb = &lds[bufi][0];                                                             \
    __builtin_amdgcn_global_load_lds(                                                     \
        (const AS1 void*)(Ab + (long)sr * lda + kk + scol),                               \
        (AS3 void*)(lb + t * 8), 16, 0, 0);                                               \
    __builtin_amdgcn_global_load_lds(                                                     \
        (const AS1 void*)(Ab + (long)(sr + 128) * lda + kk + scol),                       \
        (AS3 void*)(lb + 4096 + t * 8), 16, 0, 0);                                        \
    __builtin_amdgcn_global_load_lds(                                                     \
        (const AS1 void*)(Bb + (long)sr * ldb + kk + scol),                               \
        (AS3 void*)(lb + 8192 + t * 8), 16, 0, 0);                                        \
  }

#define PIPE_LOOP                                                                         \
  STAGE(0, 0);                                                                            \
  STAGE(1, 1);                                                                            \
  asm volatile("s_waitcnt vmcnt(3)" ::: "memory");                                        \
  __builtin_amdgcn_s_barrier();                                                           \
  __builtin_amdgcn_sched_barrier(0);                                                      \
  int rb = 0;                                                                             \
  for (int tt = 0; tt < nt; ++tt) {                                                       \
    const bf16* lb = &lds[rb][0];                                                         \
    bf16x8 af[4], bfr[4];                                                                 \
    _Pragma("unroll") for (int m = 0; m < 4; ++m)                                         \
        af[m] = *reinterpret_cast<const bf16x8*>(lb + offA[m]);                           \
    _Pragma("unroll") for (int n = 0; n < 4; ++n)                                         \
        bfr[n] = *reinterpret_cast<const bf16x8*>(lb + offB[n]);                          \
    int sb = rb + 2; if (sb >= 3) sb -= 3;                                                \
    if (tt + 2 < nt) STAGE(sb, tt + 2);                                                   \
    __builtin_amdgcn_s_setprio(1);                                                        \
    _Pragma("unroll") for (int m = 0; m < 4; ++m)                                         \
      _Pragma("unroll") for (int n = 0; n < 4; ++n)                                       \
          acc[m][n] = __builtin_amdgcn_mfma_f32_16x16x32_bf16(af[m], bfr[n], acc[m][n], 0, 0, 0); \
    __builtin_amdgcn_s_setprio(0);                                                        \
    __builtin_amdgcn_sched_barrier(0);                                                    \
    if (tt + 2 < nt)      { asm volatile("s_waitcnt vmcnt(3)" ::: "memory"); }            \
    else if (tt + 1 < nt) { asm volatile("s_waitcnt vmcnt(0)" ::: "memory"); }            \
    if (tt + 1 < nt) {                                                                    \
      __builtin_amdgcn_s_barrier();                                                       \
      __builtin_amdgcn_sched_barrier(0);                                                  \
    }                                                                                     \
    rb = (rb + 1 == 3) ? 0 : rb + 1;                                                      \
  }

// ---------------- NT GEMM 256x128 (QK projection & final P'W2^T) ----------------
template <typename OutT, bool BIAS, bool KLIM, bool RSDIV, bool QKVSC, bool SWZ>
__global__ __launch_bounds__(512, 4)
void gemm_nt(const bf16* __restrict__ A, const bf16* __restrict__ B,
             const float* __restrict__ bias, OutT* __restrict__ C,
             const float* __restrict__ rs,
             int K, int lda, int ldb, int N, long sA, long sB, long sC) {
  int bj, bi;
  if (SWZ) {
    const int lin = blockIdx.x + gridDim.x * blockIdx.y;
    const int chunk = (gridDim.x * gridDim.y) >> 3;
    const int lg = (lin & 7) * chunk + (lin >> 3);
    bj = lg % gridDim.x; bi = lg / gridDim.x;
  } else { bj = blockIdx.x; bi = blockIdx.y; }
  const int bz = blockIdx.z;
  const int t = threadIdx.x;
  const bf16* Ab = A + (long)bz * sA + (long)bi * 256 * lda;
  const bf16* Bb = B + (long)bz * sB + (long)bj * 128 * ldb;
  const int Kend = KLIM ? ((bi + 1) * 256) : K;
  const int nt = Kend >> 5;

  __shared__ bf16 lds[3][12288];
  PIPE_DECLS
  PIPE_LOOP

  const int crow = l * 4;
  const int ccol = frow;
#pragma unroll
  for (int m = 0; m < 4; ++m) {
#pragma unroll
    for (int rr = 0; rr < 4; ++rr) {
      const int rowl = wr + m * 16 + crow + rr;
      const long row = (long)bi * 256 + rowl;
      const float rsv = RSDIV ? (1.0f / rs[(long)bz * SEQL + row]) : 1.0f;
#pragma unroll
      for (int n = 0; n < 4; ++n) {
        const int coll = wc + n * 16 + ccol;
        const int colg = bj * 128 + coll;
        float v = acc[m][n][rr];
        if (RSDIV) v *= rsv;
        if (BIAS)  v += bias[colg];
        if (QKVSC) v *= (colg < HID ? 0.03125f : 1.0f);
        C[(long)bz * sC + row * N + colg] = (OutT)v;
      }
    }
  }
}

// ---------------- u_part: split-K partials of U = Wo . Wv = Wo . WvT^T ----------------
// 128x128 tile, K-slice 128 (nt=4), grid (8,8,8)=(tj,ti,ks), 256 thr, 48KB LDS (3 blk/CU).
// Per-block latency ~4us (vs 40us for full-K) -> dispatch ~6us. Writes f32 partials.
__global__ __launch_bounds__(256, 3)
void u_part(const bf16* __restrict__ WOB, const bf16* __restrict__ WvT,
            float* __restrict__ UP) {
  const int tj = blockIdx.x, ti = blockIdx.y, ks = blockIdx.z;
  const bf16* Ab = WOB + (long)ti * 128 * HID + ks * 128;
  const bf16* Bb = WvT + (long)tj * 128 * HID + ks * 128;
  const int lda = HID, ldb = HID;
  const int nt = 4;

  __shared__ bf16 lds[3][8192];  // per buf: A 128x32 + B 128x32
  const int t = threadIdx.x;
  const int lane = t & 63, wid = t >> 6;
  const int wr = (wid >> 1) * 64, wc = (wid & 1) * 64;
  const int frow = lane & 15, l = lane >> 4;
  const int sr = t >> 2;
  const int scol = (((t & 3) ^ ((t >> 3) & 3)) << 3);
  int offA[4], offB[4];
#pragma unroll
  for (int m = 0; m < 4; ++m) {
    const int r = wr + m * 16 + frow;
    offA[m] = r * 32 + ((l ^ ((r >> 1) & 3)) << 3);
  }
#pragma unroll
  for (int n = 0; n < 4; ++n) {
    const int r = wc + n * 16 + frow;
    offB[n] = 4096 + r * 32 + ((l ^ ((r >> 1) & 3)) << 3);
  }
  f32x4 acc[4][4] = {};

#define STAGE128(bufi, tile_)                                                             \
  {                                                                                       \
    const int kk = (tile_) << 5;                                                          \
    bf16* lb = &lds[bufi][0];                                                             \
    _Pragma("unroll") for (int j = 0; j < 2; ++j)                                         \
      __builtin_amdgcn_global_load_lds(                                                   \
          (const AS1 void*)(Ab + (long)(sr + j * 64) * lda + kk + scol),                  \
          (AS3 void*)(lb + j * 2048 + t * 8), 16, 0, 0);                                  \
    _Pragma("unroll") for (int j = 0; j < 2; ++j)                                         \
      __builtin_amdgcn_global_load_lds(                                                   \
          (const AS1 void*)(Bb + (long)(sr + j * 64) * ldb + kk + scol),                  \
          (AS3 void*)(lb + 4096 + j * 2048 + t * 8), 16, 0, 0);                           \
  }

  STAGE128(0, 0);
  STAGE128(1, 1);
  asm volatile("s_waitcnt vmcnt(4)" ::: "memory");
  __builtin_amdgcn_s_barrier();
  __builtin_amdgcn_sched_barrier(0);
  int rb = 0;
  for (int tt = 0; tt < nt; ++tt) {
    const bf16* lb = &lds[rb][0];
    bf16x8 af[4], bfr[4];
#pragma unroll
    for (int m = 0; m < 4; ++m) af[m] = *reinterpret_cast<const bf16x8*>(lb + offA[m]);
#pragma unroll
    for (int n = 0; n < 4; ++n) bfr[n] = *reinterpret_cast<const bf16x8*>(lb + offB[n]);
    int sb = rb + 2; if (sb >= 3) sb -= 3;
    if (tt + 2 < nt) STAGE128(sb, tt + 2);
    __builtin_amdgcn_s_setprio(1);
#pragma unroll
    for (int m = 0; m < 4; ++m)
#pragma unroll
      for (int n = 0; n < 4; ++n)
        acc[m][n] = __builtin_amdgcn_mfma_f32_16x16x32_bf16(af[m], bfr[n], acc[m][n], 0, 0, 0);
    __builtin_amdgcn_s_setprio(0);
    __builtin_amdgcn_sched_barrier(0);
    if (tt + 2 < nt)      { asm volatile("s_waitcnt vmcnt(4)" ::: "memory"); }
    else if (tt + 1 < nt) { asm volatile("s_waitcnt vmcnt(0)" ::: "memory"); }
    if (tt + 1 < nt) {
      __builtin_amdgcn_s_barrier();
      __builtin_amdgcn_sched_barrier(0);
    }
    rb = (rb + 1 == 3) ? 0 : rb + 1;
  }
#undef STAGE128

  const int crow = l * 4;
  const int ccol = frow;
  float* up = UP + ((long)ks << 20);
#pragma unroll
  for (int m = 0; m < 4; ++m) {
#pragma unroll
    for (int rr = 0; rr < 4; ++rr) {
      const int rowl = wr + m * 16 + crow + rr;
#pragma unroll
      for (int n = 0; n < 4; ++n) {
        const int coll = wc + n * 16 + ccol;
        up[(long)(ti * 128 + rowl) * HID + tj * 128 + coll] = acc[m][n][rr];
      }
    }
  }
}

// ---------------- u_reduce: UB = bf16( sum_ks UP[ks] ) ----------------
__global__ __launch_bounds__(256) void u_reduce(const float* __restrict__ UP,
                                                bf16* __restrict__ UB) {
  const int i = blockIdx.x * 256 + threadIdx.x;  // float4 index, 0..262143
  float4 s = make_float4(0.f, 0.f, 0.f, 0.f);
#pragma unroll
  for (int ks = 0; ks < 8; ++ks) {
    float4 v = reinterpret_cast<const float4*>(UP)[(ks << 18) + i];
    s.x += v.x; s.y += v.y; s.z += v.z; s.w += v.w;
  }
  bf16x4 o = { (bf16)s.x, (bf16)s.y, (bf16)s.z, (bf16)s.w };
  reinterpret_cast<bf16x4*>(UB)[i] = o;
}

// ---------------- scores + W2, one dispatch, grid (17,8,4), XCD-chunked ----------------
// Live blocks (bj <= 2bi+1): P' = exp(q.k^T) causal (max-free), bf16, + atomic row sums.
// Dead blocks (256 = exactly W2's tiles): W2 = U @ X^T (U = Wo.Wv via split-K above) —
// replaces the whole V path: out = (P' W2^T)/rs + (Wo.bv + bo).
__global__ __launch_bounds__(512, 4)
void scores_w2(const bf16* __restrict__ QK, const bf16* __restrict__ U,
               const bf16* __restrict__ X,
               bf16* __restrict__ P, bf16* __restrict__ W2, float* __restrict__ rs) {
  const int lin = blockIdx.x + 17 * blockIdx.y + 136 * blockIdx.z;  // grid (17,8,4)
  const int lg = (lin & 7) * 68 + (lin >> 3);
  const int bz = lg / 136;
  const int rem = lg % 136;
  const int bi = rem / 17, bj = rem % 17;
  const int t = threadIdx.x;
  const bool live = (bj <= 2 * bi + 1);
  const bf16 *Ab, *Bb;
  bf16* Cb;
  int lda, ldb;
  if (live) {
    Ab = QK + ((long)bz * SEQL + (long)bi * 256) * (2 * HID);
    Bb = QK + HID + ((long)bz * SEQL + (long)bj * 128) * (2 * HID);
    Cb = P + ((long)bz * SEQL + (long)bi * 256) * SEQL + bj * 128;
    lda = 2 * HID; ldb = 2 * HID;
  } else {
    const int rank = bz * 64 + (15 * bi - bi * (bi - 1)) + (bj - (2 * bi + 2));  // 0..255
    const int wz = rank >> 6, r = rank & 63, mi = r >> 4, nj = r & 15;
    Ab = U + (long)mi * 256 * HID;
    Bb = X + ((long)wz * SEQL + (long)nj * 128) * HID;
    Cb = W2 + ((long)wz * HID + (long)mi * 256) * SEQL + nj * 128;
    lda = HID; ldb = HID;
  }
  const int nt = 32;  // K = 1024

  __shared__ bf16 lds[3][12288];
  PIPE_DECLS
  PIPE_LOOP

  const int crow = l * 4;
  const int ccol = frow;
#pragma unroll
  for (int m = 0; m < 4; ++m) {
#pragma unroll
    for (int rr = 0; rr < 4; ++rr) {
      const int rowl = wr + m * 16 + crow + rr;
      float part = 0.0f;
#pragma unroll
      for (int n = 0; n < 4; ++n) {
        const int coll = wc + n * 16 + ccol;
        float v = acc[m][n][rr];
        if (live) {
          const int row = bi * 256 + rowl;
          const int col = bj * 128 + coll;
          v = (col <= row) ? __expf(v) : 0.0f;  // causal mask + max-free exp
          part += v;
        }
        Cb[(long)rowl * SEQL + coll] = (bf16)v;
      }
      if (live) {
        part += __shfl_xor(part, 1);
        part += __shfl_xor(part, 2);
        part += __shfl_xor(part, 4);
        part += __shfl_xor(part, 8);
        if (frow == 0) atomicAdd(&rs[(long)bz * SEQL + bi * 256 + rowl], part);
      }
    }
  }
}

extern "C" void kernel_launch(void* const* d_in, const int* in_sizes, int n_in,
                              void* d_out, int out_size, void* d_ws, size_t ws_size,
                              hipStream_t stream) {
  const float* x  = (const float*)d_in[0];
  const float* Wq = (const float*)d_in[1];
  const float* bq = (const float*)d_in[2];
  const float* Wk = (const float*)d_in[3];
  const float* bk = (const float*)d_in[4];
  const float* Wv = (const float*)d_in[5];
  const float* bv = (const float*)d_in[6];
  const float* Wo = (const float*)d_in[7];
  const float* bo = (const float*)d_in[8];
  float* out = (float*)d_out;

  // workspace (~136.4 MiB):
  //  [0      ,16.78M)  XB bf16 [8192][1024]
  //  [16.78M ,20.97M)  WQKB (Wq,Wk) bf16
  //  [20.97M ,+8KB)    bqkv ; [+8KB,+12KB) cbias
  //  [22.02M ,24.12M)  UB bf16 [1024][1024]
  //  [25.17M ,27.26M)  WvT bf16
  //  [33.55M ,67.11M)  QK bf16 [8192][2048]
  //  [83.89M ,100.66M) W2 bf16 [4][1024][2048]
  //  [100.66M,102.76M) WOB
  //  [102.76M,136.31M) P' bf16 [8192][2048] — UPART f32 [8][1024][1024] aliases this
  //                    region (u_part/u_reduce complete before scores_w2 writes P)
  //  [136.31M,+32KB)   RS
  char* ws = (char*)d_ws;
  bf16*  XB    = (bf16*)(ws);
  bf16*  WQKB  = (bf16*)(ws + 16777216L);
  float* bqkv  = (float*)(ws + 20971520L);
  float* cbias = (float*)(ws + 20979712L);
  bf16*  UB    = (bf16*)(ws + 22020096L);
  bf16*  WvT   = (bf16*)(ws + 25165824L);
  bf16*  QK    = (bf16*)(ws + 33554432L);
  bf16*  W2    = (bf16*)(ws + 83886080L);
  bf16*  WOB   = (bf16*)(ws + 100663296L);
  bf16*  P     = (bf16*)(ws + 102760448L);
  float* UPART = (float*)(ws + 102760448L);
  float* RS    = (float*)(ws + 136314880L);

  // 1) fused prep
  cast_all<<<11592, 256, 0, stream>>>(x, Wq, Wk, Wv, Wo, bq, bk, bv, bo,
                                      XB, WQKB, WOB, WvT, bqkv, cbias, RS);

  // 2a) U partials (split-K 8), 2b) reduce+cast to bf16
  u_part<<<dim3(8, 8, 8), 256, 0, stream>>>(WOB, WvT, UPART);
  u_reduce<<<1024, 256, 0, stream>>>(UPART, UB);

  // 3) QK projection: [8192,1024] x [2048,1024]^T; q-cols scaled 1/32 (XCD-swizzled)
  gemm_nt<bf16, true, false, false, true, true><<<dim3(16, 32, 1), 512, 0, stream>>>(
      XB, WQKB, bqkv, QK, nullptr, HID, HID, HID, 2 * HID, 0, 0, 0);

  // 4) P' = exp(q.k^T) causal + atomic row sums; dead causal slots compute W2 = U X^T
  scores_w2<<<dim3(17, 8, NB), 512, 0, stream>>>(QK, UB, XB, P, W2, RS);

  // 5) out = (P' @ W2^T)/rowsum + (Wo.bv + bo)   (causal K-limit; XCD-swizzled)
  gemm_nt<float, true, true, true, false, true><<<dim3(8, 8, NB), 512, 0, stream>>>(
      P, W2, cbias, out, RS, SEQL, SEQL, SEQL, HID,
      (long)SEQL * SEQL, (long)HID * SEQL, (long)SEQL * HID);
}